// Round 5
// baseline (529.917 us; speedup 1.0000x reference)
//
#include <hip/hip_runtime.h>

// SCF GRU: T=40, B=128, N=64, H=48, BN=8192.
// Round 5: (1) K-quarter split — thread=(j,q), 54 weight floats/thread so they
// genuinely fit in VGPRs (R4's 102-float set went to AGPRs: VGPR=124, occ 17%);
// (2) raw "s_waitcnt lgkmcnt(0); s_barrier" — __syncthreads drains vmcnt(0)
// every step, putting the ~900cy f_vel prefetch latency on the critical path;
// (3) 8-step x chunks staged in LDS, next chunk's globals issued 8 steps early.

#define T_STEPS 40
#define BB      128
#define HH      48
#define BN      8192

typedef float v2f __attribute__((ext_vector_type(2)));

__device__ __forceinline__ v2f pkfma(v2f a, v2f b, v2f c) {
    return __builtin_elementwise_fma(a, b, c);
}
__device__ __forceinline__ float sigmoid_(float x) {
    return __builtin_amdgcn_rcpf(1.0f + __expf(-x));
}
// Workgroup barrier WITHOUT vmcnt drain: LDS ordering only. The only
// cross-thread data (h, staged x) moves through LDS; global prefetch loads
// stay in flight across it.
__device__ __forceinline__ void barrier_nodrain() {
    asm volatile("s_waitcnt lgkmcnt(0)\n\ts_barrier" ::: "memory");
}

// ---- prep: blocks 0..1023 img mean (wave = channel); blocks 1024..2303 loc
// sums (wave = (t,b) pair, 1280x4 = 5120). Unchanged from R4 (passing).
__global__ __launch_bounds__(256) void k_prep(const float* __restrict__ f_img,
                                              const float* __restrict__ path,
                                              float* __restrict__ img_out,
                                              float* __restrict__ S) {
    const int wid  = threadIdx.x >> 6;
    const int lane = threadIdx.x & 63;
    if (blockIdx.x < 1024) {
        const int ch = blockIdx.x * 4 + wid;
        const float4* p = reinterpret_cast<const float4*>(f_img + (size_t)ch * 6400);
        float4 a = {0.f, 0.f, 0.f, 0.f};
#pragma unroll
        for (int i = 0; i < 25; ++i) {
            const float4 v = p[lane + i * 64];
            a.x += v.x; a.y += v.y; a.z += v.z; a.w += v.w;
        }
        float s = (a.x + a.y) + (a.z + a.w);
        for (int off = 32; off > 0; off >>= 1) s += __shfl_down(s, off, 64);
        if (lane == 0) img_out[ch] = s * (1.0f / 6400.0f);
    } else {
        const int p = (blockIdx.x - 1024) * 4 + wid;
        if (p < T_STEPS * BB) {
            const float2 v = reinterpret_cast<const float2*>(path)[(size_t)p * 64 + lane];
            float sx = v.x, sy = v.y;
            for (int off = 32; off > 0; off >>= 1) {
                sx += __shfl_down(sx, off, 64);
                sy += __shfl_down(sy, off, 64);
            }
            if (lane == 0) { S[p * 2] = sx; S[p * 2 + 1] = sy; }
        }
    }
}

// ---- main recurrence: block = 192 threads = 1 row. thread = (j = tid>>2 in
// [0,48), q = tid&3 K-quarter). Butterfly shfl_xor(1),(2) within the quad.
// LDS slot layout (72 floats): [loc2 rel2 vel16 pad4 | h48].
// x-slice per q: floats [q*6, q*6+6) of [x20|pad4]; h-slice: [q*12, q*12+12).
__global__ __launch_bounds__(192, 5) void k_gru(const float* __restrict__ path,
                                                const float* __restrict__ f_vel,
                                                const float* __restrict__ W_ih,
                                                const float* __restrict__ W_hh,
                                                const float* __restrict__ b_ih,
                                                const float* __restrict__ b_hh,
                                                const float* __restrict__ img,
                                                const float* __restrict__ S,
                                                float* __restrict__ out) {
    const int tid = threadIdx.x;
    const int j   = tid >> 2;
    const int q   = tid & 3;
    const int row = blockIdx.x;
    const int b   = row >> 6;

    __shared__ __align__(16) float sxh[8][72];

    // ---- weights: x-slice 3 v2f (zero-padded past kk=20), h-slice 6 v2f ----
    v2f wxr[3], wxz[3], wxn[3], whr[6], whz[6], whn[6];
#pragma unroll
    for (int i = 0; i < 3; ++i) {
        const int kk = q * 6 + 2 * i;
        const v2f zz = {0.f, 0.f};
        wxr[i] = (kk < 20) ? *reinterpret_cast<const v2f*>(W_ih + (j)      * 52 + kk) : zz;
        wxz[i] = (kk < 20) ? *reinterpret_cast<const v2f*>(W_ih + (48 + j) * 52 + kk) : zz;
        wxn[i] = (kk < 20) ? *reinterpret_cast<const v2f*>(W_ih + (96 + j) * 52 + kk) : zz;
    }
#pragma unroll
    for (int i = 0; i < 6; ++i) {
        const int kk = q * 12 + 2 * i;
        whr[i] = *reinterpret_cast<const v2f*>(W_hh + (j)      * 48 + kk);
        whz[i] = *reinterpret_cast<const v2f*>(W_hh + (48 + j) * 48 + kk);
        whn[i] = *reinterpret_cast<const v2f*>(W_hh + (96 + j) * 48 + kk);
    }

    // ---- seeds (q==0 only carries them; butterfly adds exactly once) ----
    float seedr, seedz, seedn, seedh;
    {
        const float* im = img + b * 32;
        float ar = b_ih[j], az = b_ih[48 + j], an = b_ih[96 + j];
#pragma unroll
        for (int c = 0; c < 32; ++c) {
            const float iv = im[c];
            ar = fmaf(iv, W_ih[(j)      * 52 + 20 + c], ar);
            az = fmaf(iv, W_ih[(48 + j) * 52 + 20 + c], az);
            an = fmaf(iv, W_ih[(96 + j) * 52 + 20 + c], an);
        }
        seedr = (q == 0) ? ar + b_hh[j]      : 0.f;
        seedz = (q == 0) ? az + b_hh[48 + j] : 0.f;
        seedn = (q == 0) ? an                : 0.f;
        seedh = (q == 0) ? b_hh[96 + j]      : 0.f;
    }

    // pin weights (54 floats; fits the (192,5) 102-VGPR budget — no AGPR detour)
#pragma unroll
    for (int i = 0; i < 3; ++i) asm volatile("" : "+v"(wxr[i]), "+v"(wxz[i]), "+v"(wxn[i]));
#pragma unroll
    for (int i = 0; i < 6; ++i) asm volatile("" : "+v"(whr[i]), "+v"(whz[i]), "+v"(whn[i]));

    // ---- init: zero pads of all slots + h0 of slot 0 ----
    if (tid < 32) sxh[tid >> 2][20 + (tid & 3)] = 0.f;
    if (q == 0)   sxh[0][24 + j] = 0.f;

    // ---- issue chunk-0 global loads (t = 0..7) ----
    float  velp;        // tid<128: vel[t0 + tid>>4][row][tid&15]
    float2 locp, Sp;    // tid 128..135: path + S for t0 + (tid-128)
    if (tid < 128) {
        velp = f_vel[((size_t)(tid >> 4) * BN + row) * 16 + (tid & 15)];
    } else if (tid < 136) {
        const int tt = tid - 128;
        locp = reinterpret_cast<const float2*>(path)[(size_t)tt * BN + row];
        Sp   = reinterpret_cast<const float2*>(S)[tt * BB + b];
    }

    float hprev = 0.0f;
    for (int t = 0; t < T_STEPS; ++t) {
        if ((t & 7) == 0) {
            if (t > 0) barrier_nodrain();   // old-chunk x reads done before restage
            // stage chunk (t..t+7) from regs into slots
            if (tid < 128) {
                sxh[tid >> 4][4 + (tid & 15)] = velp;
            } else if (tid < 136) {
                const int s = tid - 128;
                sxh[s][0] = locp.x;
                sxh[s][1] = locp.y;
                sxh[s][2] = (Sp.x - 64.0f * locp.x) * (1.0f / 63.0f);
                sxh[s][3] = (Sp.y - 64.0f * locp.y) * (1.0f / 63.0f);
            }
            // issue next chunk's loads (consumed 8 steps from now)
            int tc = t + 8; if (tc >= T_STEPS) tc = T_STEPS - 8;  // harmless reload
            if (tid < 128) {
                velp = f_vel[((size_t)(tc + (tid >> 4)) * BN + row) * 16 + (tid & 15)];
            } else if (tid < 136) {
                const int tt = tc + tid - 128;
                locp = reinterpret_cast<const float2*>(path)[(size_t)tt * BN + row];
                Sp   = reinterpret_cast<const float2*>(S)[tt * BB + b];
            }
        }
        barrier_nodrain();

        const int slot = t & 7;
        const v2f* xw = reinterpret_cast<const v2f*>(&sxh[slot][q * 6]);
        const v2f* hw = reinterpret_cast<const v2f*>(&sxh[slot][24 + q * 12]);
        v2f ar = {seedr, 0.f}, az = {seedz, 0.f}, ani = {seedn, 0.f}, anh = {seedh, 0.f};
#pragma unroll
        for (int p = 0; p < 3; ++p) {
            const v2f xv = xw[p];
            ar  = pkfma(xv, wxr[p], ar);
            az  = pkfma(xv, wxz[p], az);
            ani = pkfma(xv, wxn[p], ani);
        }
#pragma unroll
        for (int p = 0; p < 6; ++p) {
            const v2f hv = hw[p];
            ar  = pkfma(hv, whr[p], ar);
            az  = pkfma(hv, whz[p], az);
            anh = pkfma(hv, whn[p], anh);
        }
        float sr  = ar.x + ar.y;
        float sz  = az.x + az.y;
        float sni = ani.x + ani.y;
        float snh = anh.x + anh.y;
        sr  += __shfl_xor(sr, 1, 64);  sr  += __shfl_xor(sr, 2, 64);
        sz  += __shfl_xor(sz, 1, 64);  sz  += __shfl_xor(sz, 2, 64);
        sni += __shfl_xor(sni, 1, 64); sni += __shfl_xor(sni, 2, 64);
        snh += __shfl_xor(snh, 1, 64); snh += __shfl_xor(snh, 2, 64);

        const float rg = sigmoid_(sr);
        const float zg = sigmoid_(sz);
        float a = sni + rg * snh;
        a = fminf(fmaxf(a, -15.0f), 15.0f);
        const float e = __expf(-2.0f * a);
        const float cand = (1.0f - e) * __builtin_amdgcn_rcpf(1.0f + e);
        const float hn = zg * (hprev - cand) + cand;
        hprev = hn;

        // h for step t+1 into slot (t+1)&7 (its h-region idle since step t-7)
        if (q == 0) {
            sxh[(t + 1) & 7][24 + j] = hn;
        } else if (q == 1) {
            out[((size_t)t * BN + row) * HH + j] = hn;
            if (t == T_STEPS - 1)
                out[(size_t)T_STEPS * BN * HH + (size_t)row * HH + j] = hn;
        }
    }
}

extern "C" void kernel_launch(void* const* d_in, const int* in_sizes, int n_in,
                              void* d_out, int out_size, void* d_ws, size_t ws_size,
                              hipStream_t stream) {
    const float* path  = (const float*)d_in[0];
    const float* f_vel = (const float*)d_in[1];
    const float* f_img = (const float*)d_in[2];
    const float* W_ih  = (const float*)d_in[3];
    const float* W_hh  = (const float*)d_in[4];
    const float* b_ih  = (const float*)d_in[5];
    const float* b_hh  = (const float*)d_in[6];
    float* out = (float*)d_out;

    float* ws  = (float*)d_ws;
    float* img = ws;            // 4096 floats
    float* S   = ws + 4096;     // 10240 floats

    hipLaunchKernelGGL(k_prep, dim3(1024 + 1280), dim3(256), 0, stream,
                       f_img, path, img, S);
    hipLaunchKernelGGL(k_gru, dim3(BN), dim3(192), 0, stream,
                       path, f_vel, W_ih, W_hh, b_ih, b_hh, img, S, out);
}